// Round 8
// baseline (536.704 us; speedup 1.0000x reference)
//
#include <hip/hip_runtime.h>
#include <hip/hip_cooperative_groups.h>

namespace cg = cooperative_groups;

#define BCNT 16
#define TT 1024
#define DIN 384
#define H1 1024
#define H2 1024
#define KW 9

typedef __attribute__((ext_vector_type(8))) short bhalf8;   // 8 bf16 in 4 VGPRs
typedef __attribute__((ext_vector_type(4))) float f32x4;

typedef const __attribute__((address_space(1))) void* gas_ptr;
typedef __attribute__((address_space(3))) void* lds_ptr;

__device__ __forceinline__ float bf2f(unsigned short u) {
    return __uint_as_float(((unsigned int)u) << 16);
}
__device__ __forceinline__ unsigned short f2bf(float f) {
    unsigned int u = __float_as_uint(f);
    unsigned int r = (u + 0x7FFFu + ((u >> 16) & 1u)) >> 16;  // RNE
    return (unsigned short)r;
}
// mish(x) = x*tanh(log1p(e^x)) = x*(u^2+2u)/(u^2+2u+2), u=e^x (exact algebra)
__device__ __forceinline__ float mish_f(float x) {
    if (x > 20.f) return x;
    float u = __expf(x);
    float n = u * u + 2.f * u;
    return x * n / (n + 2.f);
}

// ---------------- shared-memory union (32 KB; phases reuse) ----------------
union SMem {
    struct { unsigned short Al[128 * 64]; unsigned short Bl[128 * 64]; } g;  // 32768 B
    struct { float tile[32][132]; float sred[8][32][4]; float pg[32]; } t;   // 21120 B
    struct { float red[256]; float nsh; } n;                                 //  1028 B
};

// ---------------- phase bodies (byte-identical logic to round-4 kernels) ----------------

__device__ __forceinline__ void cvt_item(
    int i, const float* __restrict__ s0, unsigned short* __restrict__ d0, int n0,
    const float* __restrict__ s1, unsigned short* __restrict__ d1, int n1,
    const float* __restrict__ s2, unsigned short* __restrict__ d2, int n2,
    float* __restrict__ zb) {
    const float* s; unsigned short* d; int j = i;
    if (i < n0) { s = s0; d = d0; }
    else if ((j = i - n0) < n1) { s = s1; d = d1; }
    else if ((j = i - n0 - n1) < n2) { s = s2; d = d2; }
    else {
        j = i - n0 - n1 - n2;   // caller guarantees j < n4_z
        ((float4*)zb)[j] = make_float4(0.f, 0.f, 0.f, 0.f);
        return;
    }
    float4 v = ((const float4*)s)[j];
    ushort4 o;
    o.x = f2bf(v.x); o.y = f2bf(v.y); o.z = f2bf(v.z); o.w = f2bf(v.w);
    ((ushort4*)d)[j] = o;
}

__device__ __forceinline__ void norm_body(SMem* sm, int idx, const float* __restrict__ d_w,
                                          const float* __restrict__ d_g,
                                          float* __restrict__ dwn_s) {
    const int b = idx / KW, k = idx % KW;
    float s = 0.f;
    for (int c = threadIdx.x; c < H1; c += 256) {
        float v = d_w[((size_t)b * H1 + c) * KW + k];
        s += v * v;
    }
    __syncthreads();                       // guard smem reuse across iterations
    sm->n.red[threadIdx.x] = s; __syncthreads();
    for (int st = 128; st > 0; st >>= 1) {
        if (threadIdx.x < st) sm->n.red[threadIdx.x] += sm->n.red[threadIdx.x + st];
        __syncthreads();
    }
    if (threadIdx.x == 0) sm->n.nsh = fmaxf(sqrtf(sm->n.red[0]), 1e-12f);
    __syncthreads();
    float n = sm->n.nsh;
    for (int c = threadIdx.x; c < H1; c += 256) {
        size_t o = ((size_t)b * H1 + c) * KW + k;
        dwn_s[o] = d_w[o] / n * d_g[b * H1 + c] * (float)TT;
    }
}

__device__ __forceinline__ void tpw_body(SMem* sm, int w, const float* __restrict__ p_w,
                                         const float* __restrict__ p_g,
                                         unsigned short* __restrict__ pwTu,
                                         float* __restrict__ sumsq) {
    const int tid = threadIdx.x;
    const int tx = tid & 31, ty = tid >> 5;          // 32 x 8
    const int c0 = (w & 31) * 32, o0 = ((w >> 5) & 7) * 128, b = w >> 8;
    __syncthreads();                       // guard smem reuse across iterations
    if (tid < 32) sm->t.pg[tid] = p_g[(size_t)b * H1 + c0 + tid];
    const float4* pw4 = (const float4*)p_w;
    float s0 = 0.f, s1 = 0.f, s2 = 0.f, s3 = 0.f;
#pragma unroll
    for (int j = 0; j < 4; j++) {
        int cl = ty + j * 8;
        float4 v = pw4[(size_t)(b * H1 + c0 + cl) * (H2 / 4) + (o0 / 4) + tx];
        *(float4*)&sm->t.tile[cl][tx * 4] = v;
        s0 += v.x * v.x; s1 += v.y * v.y; s2 += v.z * v.z; s3 += v.w * v.w;
    }
    sm->t.sred[ty][tx][0] = s0; sm->t.sred[ty][tx][1] = s1;
    sm->t.sred[ty][tx][2] = s2; sm->t.sred[ty][tx][3] = s3;
    __syncthreads();
    if (tid < 128) {
        int txo = tid >> 2, q = tid & 3;
        float t = 0.f;
#pragma unroll
        for (int r = 0; r < 8; r++) t += sm->t.sred[r][txo][q];
        atomicAdd(&sumsq[(size_t)b * H2 + o0 + txo * 4 + q], t);
    }
    const int ol = tid >> 1, half = (tid & 1) * 16;
    unsigned short outv[16];
#pragma unroll
    for (int i = 0; i < 16; i++)
        outv[i] = f2bf(sm->t.tile[half + i][ol] * sm->t.pg[half + i]);
    unsigned short* dst = &pwTu[((size_t)b * H2 + o0 + ol) * H1 + c0 + half];
    *(bhalf8*)dst = *(const bhalf8*)&outv[0];
    *(bhalf8*)&dst[8] = *(const bhalf8*)&outv[8];
}

__device__ __forceinline__ void conv_body(int w, const unsigned short* __restrict__ h,
                                          const float* __restrict__ dwn_s,
                                          const float* __restrict__ d_b,
                                          unsigned short* __restrict__ y) {
    const int tid = threadIdx.x;
    const int c = tid * 4;
    const int t0 = (w & 63) * 16;
    const int b = w >> 6;
    const ushort4* hb = (const ushort4*)(h + (size_t)b * TT * H1);
    ushort4* yb = (ushort4*)(y + (size_t)b * TT * H1);
    float kk[KW][4], db[4];
#pragma unroll
    for (int q = 0; q < 4; q++) {
        db[q] = d_b[b * H1 + c + q];
#pragma unroll
        for (int i = 0; i < KW; i++)
            kk[i][q] = dwn_s[((size_t)b * H1 + c + q) * KW + i];
    }
    float wnd[KW][4];
#pragma unroll
    for (int i = 0; i < 8; i++) {
        int t = t0 - 4 + i;
        if (t >= 0) {
            ushort4 v = hb[(size_t)t * (H1 / 4) + tid];
            wnd[i][0] = bf2f(v.x); wnd[i][1] = bf2f(v.y);
            wnd[i][2] = bf2f(v.z); wnd[i][3] = bf2f(v.w);
        } else { wnd[i][0] = wnd[i][1] = wnd[i][2] = wnd[i][3] = 0.f; }
    }
#pragma unroll
    for (int j = 0; j < 16; j++) {
        const int t = t0 + j, tl = t + 4;
        if (tl < TT) {
            ushort4 v = hb[(size_t)tl * (H1 / 4) + tid];
            wnd[8][0] = bf2f(v.x); wnd[8][1] = bf2f(v.y);
            wnd[8][2] = bf2f(v.z); wnd[8][3] = bf2f(v.w);
        } else { wnd[8][0] = wnd[8][1] = wnd[8][2] = wnd[8][3] = 0.f; }
        float a0 = db[0], a1 = db[1], a2 = db[2], a3 = db[3];
#pragma unroll
        for (int i = 0; i < KW; i++) {
            a0 += kk[i][0] * wnd[i][0]; a1 += kk[i][1] * wnd[i][1];
            a2 += kk[i][2] * wnd[i][2]; a3 += kk[i][3] * wnd[i][3];
        }
        ushort4 o;
        o.x = f2bf(a0); o.y = f2bf(a1); o.z = f2bf(a2); o.w = f2bf(a3);
        yb[(size_t)t * (H1 / 4) + tid] = o;
#pragma unroll
        for (int i = 0; i < 8; i++) {
            wnd[i][0] = wnd[i + 1][0]; wnd[i][1] = wnd[i + 1][1];
            wnd[i][2] = wnd[i + 1][2]; wnd[i][3] = wnd[i + 1][3];
        }
    }
}

// round-0/4 verified 2-phase GEMM body: 128 x TN tile, BK=64, XOR swizzle.
// MODE 0: bf16(mish(v+bias[n])); MODE 1: bf16(v*rsqrt(sumsq)+bias) batched;
// MODE 2: f32(v + bias[n] + resid).
template <int MODE, int TN>
__device__ __forceinline__ void gemm_body(
    SMem* sm, int bx, int by, int bz,
    const unsigned short* __restrict__ A, const unsigned short* __restrict__ Bm,
    void* __restrict__ Cp, int Kdim, int lda, int ldb, int ldc,
    long sA, long sB, long sC,
    const float* __restrict__ bias, int biasStride,
    const float* __restrict__ sumsq, const unsigned short* __restrict__ residbf) {
    constexpr int WN = TN / 32;
    unsigned short* Al = sm->g.Al;
    unsigned short* Bl = sm->g.Bl;

    const int tid = threadIdx.x;
    const int lane = tid & 63, wv = tid >> 6;
    const int bm = bx * 128, bn = by * TN;

    const unsigned short* Ab = A + (size_t)sA * bz;
    const unsigned short* Bb = Bm + (size_t)sB * bz;

    const int rS = lane >> 3;
    const int cS = ((lane & 7) ^ (rS & 7)) * 8;

    const int wm = (wv >> 1) * 64, wn = (wv & 1) * (TN / 2);
    const int l16 = lane & 15, quad = lane >> 4;
    const int fx = l16 & 7;

    f32x4 acc[4][WN];
#pragma unroll
    for (int i = 0; i < 4; i++)
#pragma unroll
        for (int j = 0; j < WN; j++)
#pragma unroll
            for (int r = 0; r < 4; r++) acc[i][j][r] = 0.f;

    __syncthreads();                       // guard smem union reuse
    const int ktiles = Kdim / 64;
    for (int kt = 0; kt < ktiles; ++kt) {
        const int kofs = kt * 64 + cS;
#pragma unroll
        for (int i = 0; i < 4; i++) {
            const int ch = i * 4 + wv;
            const unsigned short* ga = Ab + (size_t)(bm + ch * 8 + rS) * lda + kofs;
            __builtin_amdgcn_global_load_lds((gas_ptr)ga, (lds_ptr)&Al[ch * 512], 16, 0, 0);
        }
#pragma unroll
        for (int i = 0; i < TN / 32; i++) {
            const int ch = i * 4 + wv;
            const unsigned short* gb = Bb + (size_t)(bn + ch * 8 + rS) * ldb + kofs;
            __builtin_amdgcn_global_load_lds((gas_ptr)gb, (lds_ptr)&Bl[ch * 512], 16, 0, 0);
        }
        __syncthreads();

#pragma unroll
        for (int kk = 0; kk < 2; kk++) {
            const int cg = ((kk * 4 + quad) ^ fx) * 8;
            bhalf8 af[4], bf[WN];
#pragma unroll
            for (int mi = 0; mi < 4; mi++)
                af[mi] = *(const bhalf8*)&Al[(wm + mi * 16 + l16) * 64 + cg];
#pragma unroll
            for (int ni = 0; ni < WN; ni++)
                bf[ni] = *(const bhalf8*)&Bl[(wn + ni * 16 + l16) * 64 + cg];
#pragma unroll
            for (int mi = 0; mi < 4; mi++)
#pragma unroll
                for (int ni = 0; ni < WN; ni++)
                    acc[mi][ni] = __builtin_amdgcn_mfma_f32_16x16x32_bf16(af[mi], bf[ni],
                                                                         acc[mi][ni], 0, 0, 0);
        }
        __syncthreads();
    }

#pragma unroll
    for (int mi = 0; mi < 4; mi++)
#pragma unroll
        for (int ni = 0; ni < WN; ni++)
#pragma unroll
            for (int r = 0; r < 4; r++) {
                int gm = bm + wm + mi * 16 + quad * 4 + r;
                int gn = bn + wn + ni * 16 + l16;
                float v = acc[mi][ni][r];
                size_t cidx = (size_t)sC * bz + (size_t)gm * ldc + gn;
                if constexpr (MODE == 0) {
                    v = mish_f(v + bias[gn]);
                    ((unsigned short*)Cp)[cidx] = f2bf(v);
                } else if constexpr (MODE == 1) {
                    size_t si = (size_t)bz * biasStride + gn;
                    float rr = rsqrtf(fmaxf(sumsq[si], 1e-24f));
                    v = v * rr + bias[si];
                    ((unsigned short*)Cp)[cidx] = f2bf(v);
                } else {
                    v += bias[gn] + bf2f(residbf[cidx]);
                    ((float*)Cp)[cidx] = v;
                }
            }
}

// ---------------- fused cooperative kernel: 5 phases, 4 grid syncs ----------------
__global__ __launch_bounds__(256, 4) void k_fused(
    const float* input, const float* d_w, const float* d_g, const float* d_b,
    const float* p_w, const float* p_g, const float* p_b,
    const float* w1_w, const float* w1_b, const float* w2_w, const float* w2_b,
    float* out, float* dwn_s, float* sumsq,
    unsigned short* inbf, unsigned short* w1bf, unsigned short* w2bf,
    unsigned short* h, unsigned short* y, unsigned short* pwTu, unsigned short* zt) {
    __shared__ SMem smu;
    SMem* sm = &smu;
    cg::grid_group gg = cg::this_grid();
    const int bid = blockIdx.x, nb = gridDim.x, tid = threadIdx.x;

    // P0: f32->bf16 cvt (+ zero sumsq) grid-stride; d_w norm work-loop
    const int n4_in = BCNT * TT * DIN / 4, n4_w1 = H1 * DIN / 4, n4_w2 = DIN * H2 / 4;
    const int n4_z = BCNT * H2 / 4;
    const int tot4 = n4_in + n4_w1 + n4_w2 + n4_z;
    for (int i = bid * 256 + tid; i < tot4; i += nb * 256)
        cvt_item(i, input, inbf, n4_in, w1_w, w1bf, n4_w1, w2_w, w2bf, n4_w2, sumsq);
    for (int w = bid; w < BCNT * KW; w += nb) norm_body(sm, w, d_w, d_g, dwn_s);
    gg.sync();

    // P1: p_w transpose+sumsq (4096 tiles), then G1 (1024 tiles)
    for (int w = bid; w < 32 * 8 * BCNT; w += nb) tpw_body(sm, w, p_w, p_g, pwTu, sumsq);
    for (int w = bid; w < 128 * 8; w += nb)
        gemm_body<0, 128>(sm, w & 127, w >> 7, 0, inbf, w1bf, (void*)h,
                          DIN, DIN, DIN, H1, 0, 0, 0, w1_b, 0, nullptr, nullptr);
    gg.sync();

    // P2: depthwise conv (1024 tiles)
    for (int w = bid; w < 64 * BCNT; w += nb) conv_body(w, h, dwn_s, d_b, y);
    gg.sync();

    // P3: G2 batched, XCD-swizzled (1024 tiles)
    for (int w = bid; w < 1024; w += nb) {
        int xcd = w & 7, s = w >> 3;
        int bz = xcd * 2 + (s >> 6);
        int u = s & 63;
        gemm_body<1, 128>(sm, u & 7, u >> 3, bz, y, pwTu, (void*)zt,
                          H1, H1, H1, H2, (long)TT * H1, (long)H2 * H1, (long)TT * H2,
                          p_b, H2, sumsq, nullptr);
    }
    gg.sync();

    // P4: G3 (768 tiles)
    for (int w = bid; w < 128 * 6; w += nb)
        gemm_body<2, 64>(sm, w % 128, w / 128, 0, zt, w2bf, (void*)out,
                         H2, H2, H2, DIN, 0, 0, 0, w2_b, 0, nullptr, inbf);
}

// ---------------- fallback kernels (exact round-4 path) ----------------

__global__ __launch_bounds__(256) void k_cvt3z(
    const float* __restrict__ s0, unsigned short* __restrict__ d0, int n0,
    const float* __restrict__ s1, unsigned short* __restrict__ d1, int n1,
    const float* __restrict__ s2, unsigned short* __restrict__ d2, int n2,
    float* __restrict__ zb, int n3) {
    int i = blockIdx.x * 256 + threadIdx.x;
    if (i < n0 + n1 + n2 + n3)
        cvt_item(i, s0, d0, n0, s1, d1, n1, s2, d2, n2, zb);
}

__global__ void k_norm_dwn(const float* __restrict__ d_w, const float* __restrict__ d_g,
                           float* __restrict__ dwn_s) {
    __shared__ SMem smu;
    norm_body(&smu, blockIdx.x, d_w, d_g, dwn_s);
}

__global__ __launch_bounds__(256) void k_tpw3(const float* __restrict__ p_w,
                                              const float* __restrict__ p_g,
                                              unsigned short* __restrict__ pwTu,
                                              float* __restrict__ sumsq) {
    __shared__ SMem smu;
    int w = blockIdx.x + 32 * (blockIdx.y + 8 * blockIdx.z);
    tpw_body(&smu, w, p_w, p_g, pwTu, sumsq);
}

__global__ __launch_bounds__(256) void k_conv4(const unsigned short* __restrict__ h,
                                               const float* __restrict__ dwn_s,
                                               const float* __restrict__ d_b,
                                               unsigned short* __restrict__ y) {
    conv_body(blockIdx.x + 64 * blockIdx.z, h, dwn_s, d_b, y);
}

template <int MODE, int SWIZ, int TN>
__global__ __launch_bounds__(256, 4) void gemm_nt(
    const unsigned short* __restrict__ A, const unsigned short* __restrict__ Bm,
    void* __restrict__ Cp, int Kdim, int lda, int ldb, int ldc,
    long sA, long sB, long sC,
    const float* __restrict__ bias, int biasStride,
    const float* __restrict__ sumsq,
    const unsigned short* __restrict__ residbf) {
    __shared__ SMem smu;
    int bx, by, bz;
    if constexpr (SWIZ) {
        int l = blockIdx.x;
        int xcd = l & 7, s = l >> 3;
        bz = xcd * 2 + (s >> 6);
        int u = s & 63;
        bx = u & 7; by = u >> 3;
    } else {
        bx = blockIdx.x; by = blockIdx.y; bz = blockIdx.z;
    }
    gemm_body<MODE, TN>(&smu, bx, by, bz, A, Bm, Cp, Kdim, lda, ldb, ldc,
                        sA, sB, sC, bias, biasStride, sumsq, residbf);
}

// ---------------- launch ----------------

extern "C" void kernel_launch(void* const* d_in, const int* in_sizes, int n_in,
                              void* d_out, int out_size, void* d_ws, size_t ws_size,
                              hipStream_t stream) {
    const float* input = (const float*)d_in[0];
    const float* d_w   = (const float*)d_in[1];
    const float* d_g   = (const float*)d_in[2];
    const float* d_b   = (const float*)d_in[3];
    const float* p_w   = (const float*)d_in[4];
    const float* p_g   = (const float*)d_in[5];
    const float* p_b   = (const float*)d_in[6];
    const float* w1_w  = (const float*)d_in[7];
    const float* w1_b  = (const float*)d_in[8];
    const float* w2_w  = (const float*)d_in[9];
    const float* w2_b  = (const float*)d_in[10];
    float* out = (float*)d_out;

    char* ws = (char*)d_ws;
    size_t off = 0;
    auto alloc = [&](size_t bytes) {
        char* p = ws + off;
        off += (bytes + 255) & ~(size_t)255;
        return p;
    };
    float* dwn_s         = (float*)alloc((size_t)BCNT * H1 * KW * 4);
    float* sumsq         = (float*)alloc((size_t)BCNT * H2 * 4);
    unsigned short* inbf = (unsigned short*)alloc((size_t)BCNT * TT * DIN * 2);
    unsigned short* w1bf = (unsigned short*)alloc((size_t)H1 * DIN * 2);
    unsigned short* w2bf = (unsigned short*)alloc((size_t)DIN * H2 * 2);
    unsigned short* h    = (unsigned short*)alloc((size_t)BCNT * TT * H1 * 2);
    unsigned short* y    = (unsigned short*)alloc((size_t)BCNT * TT * H1 * 2);
    unsigned short* pwTu = (unsigned short*)alloc((size_t)BCNT * H2 * H1 * 2);
    unsigned short* zt   = (unsigned short*)alloc((size_t)BCNT * TT * H2 * 2);

    // ---- preferred: single cooperative launch (kills ~6 inter-dispatch gaps) ----
    int maxb = 0;
    hipError_t oe = hipOccupancyMaxActiveBlocksPerMultiprocessor(
        &maxb, (const void*)k_fused, 256, 0);
    if (oe != hipSuccess || maxb < 1) maxb = 2;
    int grid = maxb * 256;                 // 256 CUs on MI355X
    if (grid > 1024) grid = 1024;          // all phases sized for <=1024 tiles/loop
    void* args[] = {
        (void*)&input, (void*)&d_w, (void*)&d_g, (void*)&d_b, (void*)&p_w,
        (void*)&p_g, (void*)&p_b, (void*)&w1_w, (void*)&w1_b, (void*)&w2_w,
        (void*)&w2_b, (void*)&out, (void*)&dwn_s, (void*)&sumsq, (void*)&inbf,
        (void*)&w1bf, (void*)&w2bf, (void*)&h, (void*)&y, (void*)&pwTu, (void*)&zt};
    hipError_t le = hipLaunchCooperativeKernel((const void*)k_fused, dim3(grid),
                                               dim3(256), args, 0, stream);
    if (le == hipSuccess) return;
    (void)hipGetLastError();               // clear; fall back to 7-launch path

    // ---- fallback: exact round-4 sequence ----
    const int n4_in = BCNT * TT * DIN / 4, n4_w1 = H1 * DIN / 4, n4_w2 = DIN * H2 / 4;
    const int n4_z = BCNT * H2 / 4;
    k_cvt3z<<<(n4_in + n4_w1 + n4_w2 + n4_z + 255) / 256, 256, 0, stream>>>(
        input, inbf, n4_in, w1_w, w1bf, n4_w1, w2_w, w2bf, n4_w2, sumsq, n4_z);
    k_norm_dwn<<<BCNT * KW, 256, 0, stream>>>(d_w, d_g, dwn_s);
    k_tpw3<<<dim3(32, 8, BCNT), 256, 0, stream>>>(p_w, p_g, pwTu, sumsq);
    gemm_nt<0, 0, 128><<<dim3(BCNT * TT / 128, H1 / 128, 1), 256, 0, stream>>>(
        inbf, w1bf, h, DIN, DIN, DIN, H1, 0, 0, 0, w1_b, 0, nullptr, nullptr);
    k_conv4<<<dim3(TT / 16, 1, BCNT), 256, 0, stream>>>(h, dwn_s, d_b, y);
    gemm_nt<1, 1, 128><<<dim3(1024, 1, 1), 256, 0, stream>>>(
        y, pwTu, zt, H1, H1, H1, H2, (long)TT * H1, (long)H2 * H1, (long)TT * H2,
        p_b, H2, sumsq, nullptr);
    gemm_nt<2, 0, 64><<<dim3(BCNT * TT / 128, DIN / 64, 1), 256, 0, stream>>>(
        zt, w2bf, out, H2, H2, H2, DIN, 0, 0, 0, w2_b, 0, nullptr, inbf);
}

// Round 9
// 267.468 us; speedup vs baseline: 2.0066x; 2.0066x over previous
//
#include <hip/hip_runtime.h>

#define BCNT 16
#define TT 1024
#define DIN 384
#define H1 1024
#define H2 1024
#define KW 9

typedef __attribute__((ext_vector_type(8))) short bhalf8;   // 8 bf16 in 4 VGPRs
typedef __attribute__((ext_vector_type(4))) float f32x4;

typedef const __attribute__((address_space(1))) void* gas_ptr;
typedef __attribute__((address_space(3))) void* lds_ptr;

__device__ __forceinline__ float bf2f(unsigned short u) {
    return __uint_as_float(((unsigned int)u) << 16);
}
__device__ __forceinline__ unsigned short f2bf(float f) {
    unsigned int u = __float_as_uint(f);
    unsigned int r = (u + 0x7FFFu + ((u >> 16) & 1u)) >> 16;  // RNE
    return (unsigned short)r;
}
// mish(x) = x*tanh(log1p(e^x)) = x*(u^2+2u)/(u^2+2u+2), u=e^x (exact algebra)
__device__ __forceinline__ float mish_f(float x) {
    if (x > 20.f) return x;
    float u = __expf(x);
    float n = u * u + 2.f * u;
    return x * n / (n + 2.f);
}

// ---------------- k_prep: fused cvt + norm_dwn + tpw (one launch) ----------------
// The three prep stages have fully disjoint outputs (inbf/w1bf/w2bf, dwn_s,
// pwTu/sumsq) and only external inputs -> safe in one launch with block-range
// partitioning, no ordering required. tpw restructured: ONE block owns each
// (b, 128-o range) and loops all 32 c-tiles, accumulating sumsq in registers ->
// direct store (no atomicAdd, no pre-zeroing pass). tpw blocks take the lowest
// blockIdx so the long-running blocks dispatch first; cvt flood fills behind.
// grid = 128 (tpw) + 144 (norm) + 6912 (cvt) = 7184 blocks x 256.
__global__ __launch_bounds__(256) void k_prep(
    const float* __restrict__ input, const float* __restrict__ w1_w,
    const float* __restrict__ w2_w, const float* __restrict__ d_w,
    const float* __restrict__ d_g, const float* __restrict__ p_w,
    const float* __restrict__ p_g,
    unsigned short* __restrict__ inbf, unsigned short* __restrict__ w1bf,
    unsigned short* __restrict__ w2bf, float* __restrict__ dwn_s,
    unsigned short* __restrict__ pwTu, float* __restrict__ sumsq) {
    const int bid = blockIdx.x, tid = threadIdx.x;

    if (bid < 128) {
        // ---- tpw: transpose+scale p_w, direct sumsq (b = bid>>3, o0 = (bid&7)*128)
        __shared__ float tile[32][132];
        __shared__ float sred[8][32][4];
        const int tx = tid & 31, ty = tid >> 5;      // 32 x 8
        const int b = bid >> 3, o0 = (bid & 7) * 128;
        const float4* pw4 = (const float4*)p_w;
        float s0 = 0.f, s1 = 0.f, s2 = 0.f, s3 = 0.f;
        for (int ct = 0; ct < 32; ++ct) {
            const int c0 = ct * 32;
            __syncthreads();                          // tile overwrite guard
#pragma unroll
            for (int j = 0; j < 4; j++) {
                int cl = ty + j * 8;
                float4 v = pw4[(size_t)(b * H1 + c0 + cl) * (H2 / 4) + (o0 / 4) + tx];
                float pgv = p_g[(size_t)b * H1 + c0 + cl];
                s0 += v.x * v.x; s1 += v.y * v.y; s2 += v.z * v.z; s3 += v.w * v.w;
                v.x *= pgv; v.y *= pgv; v.z *= pgv; v.w *= pgv;
                *(float4*)&tile[cl][tx * 4] = v;      // pre-scaled for transpose
            }
            __syncthreads();
            const int ol = tid >> 1, half = (tid & 1) * 16;
            unsigned short outv[16];
#pragma unroll
            for (int i = 0; i < 16; i++) outv[i] = f2bf(tile[half + i][ol]);
            unsigned short* dst = &pwTu[((size_t)b * H2 + o0 + ol) * H1 + c0 + half];
            *(bhalf8*)dst = *(const bhalf8*)&outv[0];
            *(bhalf8*)&dst[8] = *(const bhalf8*)&outv[8];
        }
        __syncthreads();
        sred[ty][tx][0] = s0; sred[ty][tx][1] = s1;
        sred[ty][tx][2] = s2; sred[ty][tx][3] = s3;
        __syncthreads();
        if (tid < 128) {
            int txo = tid >> 2, q = tid & 3;
            float t = 0.f;
#pragma unroll
            for (int r = 0; r < 8; r++) t += sred[r][txo][q];
            sumsq[(size_t)b * H2 + o0 + txo * 4 + q] = t;   // single writer
        }
    } else if (bid < 272) {
        // ---- norm_dwn (idx = bid-128; b*KW+k over 144)
        __shared__ float red[256];
        __shared__ float nsh;
        const int idx = bid - 128;
        const int b = idx / KW, k = idx % KW;
        float s = 0.f;
        for (int c = tid; c < H1; c += 256) {
            float v = d_w[((size_t)b * H1 + c) * KW + k];
            s += v * v;
        }
        red[tid] = s; __syncthreads();
        for (int st = 128; st > 0; st >>= 1) {
            if (tid < st) red[tid] += red[tid + st];
            __syncthreads();
        }
        if (tid == 0) nsh = fmaxf(sqrtf(red[0]), 1e-12f);
        __syncthreads();
        float n = nsh;
        for (int c = tid; c < H1; c += 256) {
            size_t o = ((size_t)b * H1 + c) * KW + k;
            dwn_s[o] = d_w[o] / n * d_g[b * H1 + c] * (float)TT;
        }
    } else {
        // ---- f32->bf16 cvt: input, w1_w, w2_w (1769472 float4 items = 6912 blocks)
        const int n0 = BCNT * TT * DIN / 4, n1 = H1 * DIN / 4, n2 = DIN * H2 / 4;
        int i = (bid - 272) * 256 + tid;
        if (i >= n0 + n1 + n2) return;
        const float* s; unsigned short* d; int j = i;
        if (i < n0) { s = input; d = inbf; }
        else if ((j = i - n0) < n1) { s = w1_w; d = w1bf; }
        else { j = i - n0 - n1; s = w2_w; d = w2bf; }
        float4 v = ((const float4*)s)[j];
        ushort4 o;
        o.x = f2bf(v.x); o.y = f2bf(v.y); o.z = f2bf(v.z); o.w = f2bf(v.w);
        ((ushort4*)d)[j] = o;
    }
}

// depthwise conv along T. Vectorized: 4 channels/thread (ushort4, 8B/lane),
// t-block 16 -> grid (64,1,16) = 1024 blocks = 4 blk/CU (16 waves/CU TLP).
__global__ __launch_bounds__(256) void k_conv4(const unsigned short* __restrict__ h,
                                               const float* __restrict__ dwn_s,
                                               const float* __restrict__ d_b,
                                               unsigned short* __restrict__ y) {
    const int tid = threadIdx.x;
    const int c = tid * 4;                 // 256 threads cover H1=1024
    const int t0 = blockIdx.x * 16;
    const int b = blockIdx.z;
    const ushort4* hb = (const ushort4*)(h + (size_t)b * TT * H1);
    ushort4* yb = (ushort4*)(y + (size_t)b * TT * H1);
    float kk[KW][4], db[4];
#pragma unroll
    for (int q = 0; q < 4; q++) {
        db[q] = d_b[b * H1 + c + q];
#pragma unroll
        for (int i = 0; i < KW; i++)
            kk[i][q] = dwn_s[((size_t)b * H1 + c + q) * KW + i];
    }
    float w[KW][4];
#pragma unroll
    for (int i = 0; i < 8; i++) {
        int t = t0 - 4 + i;
        if (t >= 0) {                      // t < TT always here
            ushort4 v = hb[(size_t)t * (H1 / 4) + tid];
            w[i][0] = bf2f(v.x); w[i][1] = bf2f(v.y);
            w[i][2] = bf2f(v.z); w[i][3] = bf2f(v.w);
        } else { w[i][0] = w[i][1] = w[i][2] = w[i][3] = 0.f; }
    }
#pragma unroll
    for (int j = 0; j < 16; j++) {
        const int t = t0 + j, tl = t + 4;
        if (tl < TT) {
            ushort4 v = hb[(size_t)tl * (H1 / 4) + tid];
            w[8][0] = bf2f(v.x); w[8][1] = bf2f(v.y);
            w[8][2] = bf2f(v.z); w[8][3] = bf2f(v.w);
        } else { w[8][0] = w[8][1] = w[8][2] = w[8][3] = 0.f; }
        float a0 = db[0], a1 = db[1], a2 = db[2], a3 = db[3];
#pragma unroll
        for (int i = 0; i < KW; i++) {
            a0 += kk[i][0] * w[i][0]; a1 += kk[i][1] * w[i][1];
            a2 += kk[i][2] * w[i][2]; a3 += kk[i][3] * w[i][3];
        }
        ushort4 o;
        o.x = f2bf(a0); o.y = f2bf(a1); o.z = f2bf(a2); o.w = f2bf(a3);
        yb[(size_t)t * (H1 / 4) + tid] = o;
#pragma unroll
        for (int i = 0; i < 8; i++) {
            w[i][0] = w[i + 1][0]; w[i][1] = w[i + 1][1];
            w[i][2] = w[i + 1][2]; w[i][3] = w[i + 1][3];
        }
    }
}

// ------- bf16 NT MFMA GEMM (round-0 structure, best measured): 128 x TN tile -------
// C[m,n] = sum_k A[m,k]*B[n,k], bf16 K-contiguous. BK=64. 4 blocks/CU.
// Session verdict: this 2-phase structure at 4 blk/CU beat five deep-pipeline
// variants (44.5/49/52.4/44.6/63.6 us vs 40.1 here) and a cooperative fusion
// (695 us: register-budget collision -> spills). Cross-block TLP does the
// latency hiding; G2 runs at 94% of the structure's ~912 TF verified ceiling.
// MODE 0: C=bf16(mish(v + bias[n]))
// MODE 1: C=bf16(v*rsqrt(sumsq[bz*str+n]) + bias[bz*str+n])
// MODE 2: C=f32 (v + bias[n] + bf2f(residbf[idx]))
template <int MODE, int SWIZ, int TN>
__global__ __launch_bounds__(256, 4) void gemm_nt(
    const unsigned short* __restrict__ A, const unsigned short* __restrict__ Bm,
    void* __restrict__ Cp, int Kdim, int lda, int ldb, int ldc,
    long sA, long sB, long sC,
    const float* __restrict__ bias, int biasStride,
    const float* __restrict__ sumsq,
    const unsigned short* __restrict__ residbf) {
    constexpr int WN = TN / 32;                    // B frags per wave (4 or 2)
    __shared__ __attribute__((aligned(16))) unsigned short Al[128 * 64];
    __shared__ __attribute__((aligned(16))) unsigned short Bl[TN * 64];

    const int tid = threadIdx.x;
    const int lane = tid & 63, wv = tid >> 6;      // 4 waves

    int bx, by, bz;
    if constexpr (SWIZ) {
        // G2: 1024 blocks. XCD k owns batches {2k,2k+1}; m-tile fastest.
        int l = blockIdx.x;
        int xcd = l & 7, s = l >> 3;               // s: 0..127
        bz = xcd * 2 + (s >> 6);
        int u = s & 63;
        bx = u & 7; by = u >> 3;
    } else {
        bx = blockIdx.x; by = blockIdx.y; bz = blockIdx.z;
    }
    const int bm = bx * 128, bn = by * TN;

    const unsigned short* Ab = A + (size_t)sA * bz;
    const unsigned short* Bb = Bm + (size_t)sB * bz;

    // staging lane map (XOR swizzle on source column)
    const int rS = lane >> 3;                       // row within 8-row chunk
    const int cS = ((lane & 7) ^ (rS & 7)) * 8;     // global col-group offset (elems)

    const int wm = (wv >> 1) * 64, wn = (wv & 1) * (TN / 2);
    const int l16 = lane & 15, quad = lane >> 4;
    const int fx = l16 & 7;                         // read-side XOR key

    f32x4 acc[4][WN];
#pragma unroll
    for (int i = 0; i < 4; i++)
#pragma unroll
        for (int j = 0; j < WN; j++)
#pragma unroll
            for (int r = 0; r < 4; r++) acc[i][j][r] = 0.f;

    const int ktiles = Kdim / 64;
    for (int kt = 0; kt < ktiles; ++kt) {
        const int kofs = kt * 64 + cS;
        // A: 16 chunks of 8 rows, 4 per wave
#pragma unroll
        for (int i = 0; i < 4; i++) {
            const int ch = i * 4 + wv;
            const unsigned short* ga = Ab + (size_t)(bm + ch * 8 + rS) * lda + kofs;
            __builtin_amdgcn_global_load_lds((gas_ptr)ga, (lds_ptr)&Al[ch * 512], 16, 0, 0);
        }
        // B: TN/8 chunks, TN/32 per wave
#pragma unroll
        for (int i = 0; i < TN / 32; i++) {
            const int ch = i * 4 + wv;
            const unsigned short* gb = Bb + (size_t)(bn + ch * 8 + rS) * ldb + kofs;
            __builtin_amdgcn_global_load_lds((gas_ptr)gb, (lds_ptr)&Bl[ch * 512], 16, 0, 0);
        }
        __syncthreads();

#pragma unroll
        for (int kk = 0; kk < 2; kk++) {
            const int cg = ((kk * 4 + quad) ^ fx) * 8;   // swizzled col offset
            bhalf8 af[4], bf[WN];
#pragma unroll
            for (int mi = 0; mi < 4; mi++)
                af[mi] = *(const bhalf8*)&Al[(wm + mi * 16 + l16) * 64 + cg];
#pragma unroll
            for (int ni = 0; ni < WN; ni++)
                bf[ni] = *(const bhalf8*)&Bl[(wn + ni * 16 + l16) * 64 + cg];
#pragma unroll
            for (int mi = 0; mi < 4; mi++)
#pragma unroll
                for (int ni = 0; ni < WN; ni++)
                    acc[mi][ni] = __builtin_amdgcn_mfma_f32_16x16x32_bf16(af[mi], bf[ni],
                                                                         acc[mi][ni], 0, 0, 0);
        }
        __syncthreads();
    }

    // epilogue: D row = quad*4+r, col = lane&15
#pragma unroll
    for (int mi = 0; mi < 4; mi++)
#pragma unroll
        for (int ni = 0; ni < WN; ni++)
#pragma unroll
            for (int r = 0; r < 4; r++) {
                int gm = bm + wm + mi * 16 + quad * 4 + r;
                int gn = bn + wn + ni * 16 + l16;
                float v = acc[mi][ni][r];
                size_t cidx = (size_t)sC * bz + (size_t)gm * ldc + gn;
                if constexpr (MODE == 0) {
                    v = mish_f(v + bias[gn]);
                    ((unsigned short*)Cp)[cidx] = f2bf(v);
                } else if constexpr (MODE == 1) {
                    size_t si = (size_t)bz * biasStride + gn;
                    float rr = rsqrtf(fmaxf(sumsq[si], 1e-24f));
                    v = v * rr + bias[si];
                    ((unsigned short*)Cp)[cidx] = f2bf(v);
                } else {
                    v += bias[gn] + bf2f(residbf[cidx]);
                    ((float*)Cp)[cidx] = v;
                }
            }
}

// ---------------- launch ----------------

extern "C" void kernel_launch(void* const* d_in, const int* in_sizes, int n_in,
                              void* d_out, int out_size, void* d_ws, size_t ws_size,
                              hipStream_t stream) {
    const float* input = (const float*)d_in[0];
    const float* d_w   = (const float*)d_in[1];
    const float* d_g   = (const float*)d_in[2];
    const float* d_b   = (const float*)d_in[3];
    const float* p_w   = (const float*)d_in[4];
    const float* p_g   = (const float*)d_in[5];
    const float* p_b   = (const float*)d_in[6];
    const float* w1_w  = (const float*)d_in[7];
    const float* w1_b  = (const float*)d_in[8];
    const float* w2_w  = (const float*)d_in[9];
    const float* w2_b  = (const float*)d_in[10];
    float* out = (float*)d_out;

    char* ws = (char*)d_ws;
    size_t off = 0;
    auto alloc = [&](size_t bytes) {
        char* p = ws + off;
        off += (bytes + 255) & ~(size_t)255;
        return p;
    };
    float* dwn_s         = (float*)alloc((size_t)BCNT * H1 * KW * 4);
    float* sumsq         = (float*)alloc((size_t)BCNT * H2 * 4);
    unsigned short* inbf = (unsigned short*)alloc((size_t)BCNT * TT * DIN * 2);
    unsigned short* w1bf = (unsigned short*)alloc((size_t)H1 * DIN * 2);
    unsigned short* w2bf = (unsigned short*)alloc((size_t)DIN * H2 * 2);
    unsigned short* h    = (unsigned short*)alloc((size_t)BCNT * TT * H1 * 2);
    unsigned short* y    = (unsigned short*)alloc((size_t)BCNT * TT * H1 * 2);
    unsigned short* pwTu = (unsigned short*)alloc((size_t)BCNT * H2 * H1 * 2);
    unsigned short* zt   = (unsigned short*)alloc((size_t)BCNT * TT * H2 * 2);

    // prep (fused, 1 launch): cvt input/w1/w2 -> bf16, norm d_w, transpose p_w
    // + direct sumsq (no atomics/zeroing). 128 tpw + 144 norm + 6912 cvt blocks.
    k_prep<<<7184, 256, 0, stream>>>(input, w1_w, w2_w, d_w, d_g, p_w, p_g,
                                     inbf, w1bf, w2bf, dwn_s, pwTu, sumsq);

    // G1: h = bf16(mish(input @ w1_w^T + w1_b)), (B*T, H1); 1024 blocks, 6 K-iters
    gemm_nt<0, 0, 128><<<dim3(BCNT * TT / 128, H1 / 128, 1), 256, 0, stream>>>(
        inbf, w1bf, h, DIN, DIN, DIN, H1, 0, 0, 0, w1_b, 0, nullptr, nullptr);

    // depthwise conv -> y (B*T, H1) bf16; 1024 blocks, 4ch/thread
    k_conv4<<<dim3(TT / 16, 1, BCNT), 256, 0, stream>>>(h, dwn_s, d_b, y);

    // G2 (batched, XCD-swizzled, 1024 blocks): zt = rsqrt(sumsq)*(y.pwTu) + p_b
    gemm_nt<1, 1, 128><<<dim3(1024, 1, 1), 256, 0, stream>>>(
        y, pwTu, zt, H1, H1, H1, H2, (long)TT * H1, (long)H2 * H1, (long)TT * H2,
        p_b, H2, sumsq, nullptr);

    // G3: out = zt @ w2^T + w2_b + resid; 128x64 tiles -> 768 blocks
    gemm_nt<2, 0, 64><<<dim3(BCNT * TT / 128, DIN / 64, 1), 256, 0, stream>>>(
        zt, w2bf, out, H2, H2, H2, DIN, 0, 0, 0, w2_b, 0, nullptr, inbf);
}